// Round 18
// baseline (362.208 us; speedup 1.0000x reference)
//
#include <hip/hip_runtime.h>

// FFF tree traversal, round 18: BUCKETED TWO-PHASE. r13-r17 pinned at ~75us
// main with nothing saturated -> latency wall on sign-dependent weight
// gathers (deep rows at L3 latency). Restructure so weights are LDS-resident:
//   phase1: levels 0-5 from LDS (w1 rows 0..62 = 63KB); emits xq + stx +
//           node6 + 6 scores; histogram of node6 (64 buckets).
//   sort  : exclusive scan + scatter -> perm[] grouped by node6.
//   phase2: per bucket, stage the 31-node level-6..10 subtree (w1+w2, 62KB)
//           in LDS; traverse + full 11-term y-accum (shallow w2 = 6
//           block-hot global gathers; all 11 terms independent -> MLP).
// Arithmetic order identical to r16 -> absmax unchanged (0.0234).
// Falls back to the proven r16 single-kernel (75us) if ws < 39 MB.

typedef float        f32x4 __attribute__((ext_vector_type(4)));
typedef unsigned int u32x4 __attribute__((ext_vector_type(4)));

#define FFF_BATCH  32768
#define FFF_NIN    1024
#define FFF_NOUT   1024
#define FFF_LEVELS 11
#define FFF_NODES  2047
#define FFF_EPS    0.035f

__device__ __forceinline__ f32x4 ld_nt4f(const f32x4* p) { return __builtin_nontemporal_load(p); }
__device__ __forceinline__ float ub(unsigned d, int k) {
    return (float)((d >> (8 * k)) & 0xffu);   // -> v_cvt_f32_ubyte[k]
}

__device__ __forceinline__ int sdot4(unsigned a, unsigned b, int c) {
#if __has_builtin(__builtin_amdgcn_sdot4)
    return __builtin_amdgcn_sdot4((int)a, (int)b, c, false);
#else
#pragma unroll
    for (int k = 0; k < 4; ++k) {
        const int ai = (int)(a << (24 - 8 * k)) >> 24;
        const int bi = (int)(b << (24 - 8 * k)) >> 24;
        c += ai * bi;
    }
    return c;
#endif
}

template<int CTRL>
__device__ __forceinline__ float dpp_add(float v) {
    const int t = __builtin_amdgcn_update_dpp(0, __float_as_int(v), CTRL, 0xF, 0xF, true);
    return v + __int_as_float(t);
}
__device__ __forceinline__ float wave_sum(float v) {
    v = dpp_add<0x111>(v); v = dpp_add<0x112>(v);
    v = dpp_add<0x114>(v); v = dpp_add<0x118>(v);
    v = dpp_add<0x142>(v); v = dpp_add<0x143>(v);
    return __int_as_float(__builtin_amdgcn_readlane(__float_as_int(v), 63));
}
template<int CTRL>
__device__ __forceinline__ int dpp_addi(int v) {
    return v + __builtin_amdgcn_update_dpp(0, v, CTRL, 0xF, 0xF, true);
}
__device__ __forceinline__ int wave_sum_i(int v) {
    v = dpp_addi<0x111>(v); v = dpp_addi<0x112>(v);
    v = dpp_addi<0x114>(v); v = dpp_addi<0x118>(v);
    v = dpp_addi<0x142>(v); v = dpp_addi<0x143>(v);
    return __builtin_amdgcn_readlane(v, 63);
}
template<int CTRL>
__device__ __forceinline__ float dpp_max(float v) {
    const int t = __builtin_amdgcn_update_dpp(0, __float_as_int(v), CTRL, 0xF, 0xF, true);
    return fmaxf(v, __int_as_float(t));
}
__device__ __forceinline__ float wave_max(float v) {   // v >= 0
    v = dpp_max<0x111>(v); v = dpp_max<0x112>(v);
    v = dpp_max<0x114>(v); v = dpp_max<0x118>(v);
    v = dpp_max<0x142>(v); v = dpp_max<0x143>(v);
    return __int_as_float(__builtin_amdgcn_readlane(__float_as_int(v), 63));
}

// ---- prep: w1 -> signed i8, w2 -> biased u8 (r16 verbatim) ----
__global__ void fff_quant_u8(const float* __restrict__ w1, const float* __restrict__ w2,
                             unsigned char* __restrict__ q1, unsigned char* __restrict__ q2,
                             float* __restrict__ s1, float* __restrict__ s2)
{
    const int node = blockIdx.x;
    const int t    = threadIdx.x;          // 256
    const int wave = t >> 6;
    const int lane = t & 63;

    const f32x4* r1 = reinterpret_cast<const f32x4*>(w1 + (size_t)node * FFF_NIN);
    const f32x4* r2 = reinterpret_cast<const f32x4*>(w2 + (size_t)node * FFF_NOUT);
    const int si = 64 * (t & 3) + (t >> 2);
    const f32x4 v1 = r1[si];
    const f32x4 v2 = r2[si];

    float m1 = 0.f, m2 = 0.f;
#pragma unroll
    for (int k = 0; k < 4; ++k) {
        m1 = fmaxf(m1, fabsf(v1[k]));
        m2 = fmaxf(m2, fabsf(v2[k]));
    }
#pragma unroll
    for (int m = 1; m < 64; m <<= 1) {
        m1 = fmaxf(m1, __shfl_xor(m1, m, 64));
        m2 = fmaxf(m2, __shfl_xor(m2, m, 64));
    }
    __shared__ float sm1[4], sm2[4];
    if (lane == 0) { sm1[wave] = m1; sm2[wave] = m2; }
    __syncthreads();
    m1 = fmaxf(fmaxf(sm1[0], sm1[1]), fmaxf(sm1[2], sm1[3]));
    m2 = fmaxf(fmaxf(sm2[0], sm2[1]), fmaxf(sm2[2], sm2[3]));

    const float st1 = (m1 > 0.f) ? m1 / 127.f : 1.f;
    const float st2 = (m2 > 0.f) ? m2 / 127.f : 1.f;
    if (t == 0) { s1[node] = st1; s2[node] = st2; }

    unsigned d1 = 0, d2 = 0;
#pragma unroll
    for (int k = 0; k < 4; ++k) {
        const int i1 = (int)rintf(v1[k] / st1);
        const int u2 = (int)rintf(v2[k] / st2) + 128;
        d1 |= ((unsigned)i1 & 0xffu) << (8 * k);
        d2 |= ((unsigned)u2 & 0xffu) << (8 * k);
    }
    reinterpret_cast<unsigned*>(q1)[(size_t)node * 256 + t] = d1;
    reinterpret_cast<unsigned*>(q2)[(size_t)node * 256 + t] = d2;
}

__global__ void fff_zero(int* __restrict__ hist) {
    if (threadIdx.x < 64) hist[threadIdx.x] = 0;
}

// ---- phase 1: levels 0..5 from LDS; emit xq/meta/hist ----
__global__ __launch_bounds__(512, 4) void fff_phase1(
    const float*         __restrict__ x,
    const unsigned char* __restrict__ q1,
    const float*         __restrict__ s1,
    const float*         __restrict__ w1f,
    u32x4*               __restrict__ xqs4,   // [row*64 + lane]
    float*               __restrict__ meta,   // [row*8]: stx, node6, sc0..5
    int*                 __restrict__ hist)
{
    __shared__ unsigned char lw1[63 * 1024];
    __shared__ float ls1[63];

    const int tid = threadIdx.x;
    // stage w1 rows 0..62 (contiguous 63KB) into LDS
    for (int i = tid; i < 63 * 64; i += 512)
        reinterpret_cast<u32x4*>(lw1)[i] = reinterpret_cast<const u32x4*>(q1)[i];
    if (tid < 63) ls1[tid] = s1[tid];
    __syncthreads();

    const int wave = tid >> 6;
    const int lane = tid & 63;
    const int gwave = blockIdx.x * 8 + wave;   // 4096 waves total

#pragma unroll 1
    for (int r = gwave; r < FFF_BATCH; r += 4096) {
        const f32x4* x4 = reinterpret_cast<const f32x4*>(x + (size_t)r * FFF_NIN);

        // i8 quantization of x
        unsigned xq[4];
        float stx;
        {
            f32x4 xv[4];
#pragma unroll
            for (int c = 0; c < 4; ++c) xv[c] = ld_nt4f(&x4[c * 64 + lane]);
            float mx = 0.f;
#pragma unroll
            for (int c = 0; c < 4; ++c)
#pragma unroll
                for (int k = 0; k < 4; ++k) mx = fmaxf(mx, fabsf(xv[c][k]));
            mx = wave_max(mx);
            stx = (mx > 0.f) ? mx / 127.f : 1.f;
            const float inv = (mx > 0.f) ? 127.f / mx : 0.f;
#pragma unroll
            for (int c = 0; c < 4; ++c) {
                unsigned pk = 0;
#pragma unroll
                for (int k = 0; k < 4; ++k)
                    pk |= ((unsigned)(int)rintf(xv[c][k] * inv) & 0xffu) << (8 * k);
                xq[c] = pk;
            }
        }
        u32x4 xw; xw[0] = xq[0]; xw[1] = xq[1]; xw[2] = xq[2]; xw[3] = xq[3];
        xqs4[(size_t)r * 64 + lane] = xw;

        // traverse levels 0..5 from LDS
        int node = 0;
        float sc0, sc1_, sc2, sc3, sc4, sc5;
#pragma unroll
        for (int l = 0; l < 6; ++l) {
            const u32x4 d1 = *reinterpret_cast<const u32x4*>(lw1 + (size_t)node * 1024 + lane * 16);
            int idot = 0;
#pragma unroll
            for (int c = 0; c < 4; ++c) idot = sdot4(xq[c], d1[c], idot);
            float p = (float)wave_sum_i(idot) * (stx * ls1[node]);

            if (__builtin_expect(fabsf(p) < FFF_EPS, 0)) {
                const f32x4* w14 = reinterpret_cast<const f32x4*>(w1f + (size_t)node * FFF_NIN);
                float s = 0.f;
#pragma unroll
                for (int c = 0; c < 4; ++c) {
                    const f32x4 xc = ld_nt4f(&x4[c * 64 + lane]);
                    const f32x4 w  = w14[c * 64 + lane];
                    s = fmaf(xc[0], w[0], s); s = fmaf(xc[1], w[1], s);
                    s = fmaf(xc[2], w[2], s); s = fmaf(xc[3], w[3], s);
                }
                p = wave_sum(s);
            }

            if (l == 0) sc0 = p; else if (l == 1) sc1_ = p; else if (l == 2) sc2 = p;
            else if (l == 3) sc3 = p; else if (l == 4) sc4 = p; else sc5 = p;
            node = 2 * node + 1 + ((p > 0.f) ? 1 : 0);
        }

        // meta: [stx, node6, sc0..5]
        float mv = stx;
        mv = (lane == 1) ? __int_as_float(node) : mv;
        mv = (lane == 2) ? sc0 : mv;  mv = (lane == 3) ? sc1_ : mv;
        mv = (lane == 4) ? sc2 : mv;  mv = (lane == 5) ? sc3 : mv;
        mv = (lane == 6) ? sc4 : mv;  mv = (lane == 7) ? sc5 : mv;
        if (lane < 8) meta[(size_t)r * 8 + lane] = mv;
        if (lane == 0) atomicAdd(&hist[node - 63], 1);
    }
}

// ---- scan: start[] = exclusive scan of hist; cursor[] = start[] ----
__global__ void fff_scan(const int* __restrict__ hist, int* __restrict__ start,
                         int* __restrict__ cursor)
{
    if (threadIdx.x == 0) {
        int acc = 0;
        for (int b = 0; b < 64; ++b) { start[b] = acc; cursor[b] = acc; acc += hist[b]; }
    }
}

// ---- scatter: perm grouped by bucket ----
__global__ void fff_scatter(const float* __restrict__ meta, int* __restrict__ cursor,
                            int* __restrict__ perm)
{
    const int r = blockIdx.x * blockDim.x + threadIdx.x;
    const int n6 = __float_as_int(meta[(size_t)r * 8 + 1]);
    const int idx = atomicAdd(&cursor[n6 - 63], 1);
    perm[idx] = r;
}

// ---- phase 2: levels 6..10 from the bucket subtree in LDS + full y-accum ----
__global__ __launch_bounds__(512, 4) void fff_phase2(
    const float*         __restrict__ x,
    const float*         __restrict__ w1f,
    const unsigned char* __restrict__ q1,
    const unsigned char* __restrict__ q2,
    const float*         __restrict__ s1,
    const float*         __restrict__ s2,
    const u32x4*         __restrict__ xqs4,
    const float*         __restrict__ meta,
    const int*           __restrict__ perm,
    const int*           __restrict__ start_,
    float*               __restrict__ y)
{
    __shared__ unsigned char lw1[31 * 1024];
    __shared__ unsigned char lw2[31 * 1024];
    __shared__ float ls1[31], ls2[31], ps2[6];
    __shared__ int   panc[6];

    const int tid   = threadIdx.x;
    const int b     = blockIdx.x >> 3;       // bucket
    const int chunk = blockIdx.x & 7;
    const int n6    = 63 + b;

    // stage the 31-node subtree: linear j (0..30) -> depth d, global row g
    for (int i = tid; i < 31 * 64; i += 512) {
        const int j   = i >> 6;
        const int off = i & 63;
        const int d   = 31 - __builtin_clz((unsigned)(j + 1));
        const int g   = ((n6 + 1) << d) - 1 + (j + 1 - (1 << d));
        reinterpret_cast<u32x4*>(lw1)[i] =
            *reinterpret_cast<const u32x4*>(q1 + (size_t)g * 1024 + off * 16);
        reinterpret_cast<u32x4*>(lw2)[i] =
            *reinterpret_cast<const u32x4*>(q2 + (size_t)g * 1024 + off * 16);
    }
    if (tid < 31) {
        const int j = tid;
        const int d = 31 - __builtin_clz((unsigned)(j + 1));
        const int g = ((n6 + 1) << d) - 1 + (j + 1 - (1 << d));
        ls1[j] = s1[g];
        ls2[j] = s2[g];
    }
    if (tid < 6) {
        int n = n6;
        for (int s = 0; s < 6 - tid; ++s) n = (n - 1) >> 1;
        panc[tid] = n;
        ps2[tid]  = s2[n];
    }
    __syncthreads();

    const int wave = tid >> 6;
    const int lane = tid & 63;
    const int cnt  = ((b < 63) ? start_[b + 1] : FFF_BATCH) - start_[b];
    const int cs   = (cnt + 7) >> 3;
    const int begin = start_[b] + chunk * cs;
    const int end   = min(begin + cs, start_[b] + cnt);

#pragma unroll 1
    for (int i = begin + wave; i < end; i += 8) {
        const int row = perm[i];
        const float* m8 = meta + (size_t)row * 8;
        const float stx = m8[0];
        float scl0 = m8[2], scl1 = m8[3], scl2 = m8[4],
              scl3 = m8[5], scl4 = m8[6], scl5 = m8[7];

        const u32x4 xw = xqs4[(size_t)row * 64 + lane];
        unsigned xq[4] = { xw[0], xw[1], xw[2], xw[3] };

        // traverse levels 6..10 from LDS
        int slot = 0, node = n6;
        int ds0, ds1, ds2, ds3, ds4;
        float sd0, sd1, sd2, sd3, sd4;
#pragma unroll
        for (int d = 0; d < 5; ++d) {
            const u32x4 d1 = *reinterpret_cast<const u32x4*>(lw1 + (size_t)slot * 1024 + lane * 16);
            int idot = 0;
#pragma unroll
            for (int c = 0; c < 4; ++c) idot = sdot4(xq[c], d1[c], idot);
            float p = (float)wave_sum_i(idot) * (stx * ls1[slot]);

            if (__builtin_expect(fabsf(p) < FFF_EPS, 0)) {
                const f32x4* x4  = reinterpret_cast<const f32x4*>(x + (size_t)row * FFF_NIN);
                const f32x4* w14 = reinterpret_cast<const f32x4*>(w1f + (size_t)node * FFF_NIN);
                float s = 0.f;
#pragma unroll
                for (int c = 0; c < 4; ++c) {
                    const f32x4 xc = ld_nt4f(&x4[c * 64 + lane]);
                    const f32x4 w  = w14[c * 64 + lane];
                    s = fmaf(xc[0], w[0], s); s = fmaf(xc[1], w[1], s);
                    s = fmaf(xc[2], w[2], s); s = fmaf(xc[3], w[3], s);
                }
                p = wave_sum(s);
            }

            if (d == 0) { ds0 = slot; sd0 = p; } else if (d == 1) { ds1 = slot; sd1 = p; }
            else if (d == 2) { ds2 = slot; sd2 = p; } else if (d == 3) { ds3 = slot; sd3 = p; }
            else { ds4 = slot; sd4 = p; }
            const int bit = (p > 0.f) ? 1 : 0;
            slot = 2 * slot + 1 + bit;
            node = 2 * node + 1 + bit;
        }

        // ---- y accumulate: levels 0..10 in order (same fp32 order as r16) ----
        f32x4 acc[4];
#pragma unroll
        for (int c = 0; c < 4; ++c) acc[c] = (f32x4)(0.f);
        float corr = 0.f;

        // shallow w2: 6 independent block-hot global gathers, issued upfront
        u32x4 g2[6];
#pragma unroll
        for (int l = 0; l < 6; ++l)
            g2[l] = *reinterpret_cast<const u32x4*>(q2 + (size_t)panc[l] * 1024 + lane * 16);

#pragma unroll
        for (int l = 0; l < 6; ++l) {
            const float sl = (l == 0) ? scl0 : (l == 1) ? scl1 : (l == 2) ? scl2
                           : (l == 3) ? scl3 : (l == 4) ? scl4 : scl5;
            const float f = sl * ps2[l];
            corr = fmaf(f, 128.f, corr);
#pragma unroll
            for (int c = 0; c < 4; ++c)
#pragma unroll
                for (int k = 0; k < 4; ++k)
                    acc[c][k] = fmaf(f, ub(g2[l][c], k), acc[c][k]);
        }

#pragma unroll
        for (int d = 0; d < 5; ++d) {
            const int   sl = (d == 0) ? ds0 : (d == 1) ? ds1 : (d == 2) ? ds2 : (d == 3) ? ds3 : ds4;
            const float sp = (d == 0) ? sd0 : (d == 1) ? sd1 : (d == 2) ? sd2 : (d == 3) ? sd3 : sd4;
            const u32x4 d2 = *reinterpret_cast<const u32x4*>(lw2 + (size_t)sl * 1024 + lane * 16);
            const float f = sp * ls2[sl];
            corr = fmaf(f, 128.f, corr);
#pragma unroll
            for (int c = 0; c < 4; ++c)
#pragma unroll
                for (int k = 0; k < 4; ++k)
                    acc[c][k] = fmaf(f, ub(d2[c], k), acc[c][k]);
        }

        f32x4* y4 = reinterpret_cast<f32x4*>(y + (size_t)row * FFF_NOUT);
#pragma unroll
        for (int c = 0; c < 4; ++c) {
            f32x4 o;
            o[0] = acc[c][0] - corr; o[1] = acc[c][1] - corr;
            o[2] = acc[c][2] - corr; o[3] = acc[c][3] - corr;
            __builtin_nontemporal_store(o, &y4[c * 64 + lane]);
        }
    }
}

// ---- r16 single-kernel path (proven 75us main) for smaller workspaces ----
__global__ __launch_bounds__(256, 8) void fff_main_u8(
    const float*         __restrict__ x,
    const unsigned char* __restrict__ q1,
    const float*         __restrict__ s1,
    const float*         __restrict__ w1f,
    const unsigned char* __restrict__ q2,
    const float*         __restrict__ s2,
    float*               __restrict__ y)
{
    const int row  = blockIdx.x * 4 + (threadIdx.x >> 6);
    const int lane = threadIdx.x & 63;

    const f32x4* x4 = reinterpret_cast<const f32x4*>(x + (size_t)row * FFF_NIN);
    f32x4 xv[4];
#pragma unroll
    for (int c = 0; c < 4; ++c) xv[c] = ld_nt4f(&x4[c * 64 + lane]);

    float mx = 0.f;
#pragma unroll
    for (int c = 0; c < 4; ++c)
#pragma unroll
        for (int k = 0; k < 4; ++k) mx = fmaxf(mx, fabsf(xv[c][k]));
    mx = wave_max(mx);
    const float stx = (mx > 0.f) ? mx / 127.f : 1.f;
    const float inv = (mx > 0.f) ? 127.f / mx : 0.f;

    unsigned xq[4];
#pragma unroll
    for (int c = 0; c < 4; ++c) {
        unsigned pk = 0;
#pragma unroll
        for (int k = 0; k < 4; ++k)
            pk |= ((unsigned)(int)rintf(xv[c][k] * inv) & 0xffu) << (8 * k);
        xq[c] = pk;
    }

    f32x4 acc[4];
#pragma unroll
    for (int c = 0; c < 4; ++c) acc[c] = (f32x4)(0.f);
    float corr = 0.f;

    const u32x4* q1v = reinterpret_cast<const u32x4*>(q1);
    const u32x4* q2v = reinterpret_cast<const u32x4*>(q2);

    int node = 0;
    u32x4 d1 = q1v[lane];
    u32x4 d2 = q2v[lane];
    float sc1 = s1[0];
    float sc2 = s2[0];

#pragma unroll 1
    for (int l = 0; l < FFF_LEVELS; ++l) {
        int idot = 0;
#pragma unroll
        for (int c = 0; c < 4; ++c) idot = sdot4(xq[c], d1[c], idot);
        float p = (float)wave_sum_i(idot) * (stx * sc1);

        if (__builtin_expect(fabsf(p) < FFF_EPS, 0)) {
            const f32x4* w14 = reinterpret_cast<const f32x4*>(w1f + (size_t)node * FFF_NIN);
            float s = 0.f;
#pragma unroll
            for (int c = 0; c < 4; ++c) {
                const f32x4 w = w14[c * 64 + lane];
                s = fmaf(xv[c][0], w[0], s); s = fmaf(xv[c][1], w[1], s);
                s = fmaf(xv[c][2], w[2], s); s = fmaf(xv[c][3], w[3], s);
            }
            p = wave_sum(s);
        }

        const int next = 2 * node + 1 + ((p > 0.f) ? 1 : 0);
        u32x4 nd1 = d1, nd2 = d2;
        float ns1 = sc1, ns2 = sc2;
        if (l < FFF_LEVELS - 1) {
            const int un = __builtin_amdgcn_readfirstlane(next);
            nd1 = q1v[(size_t)un * 64 + lane];
            nd2 = q2v[(size_t)un * 64 + lane];
            ns1 = s1[un];
            ns2 = s2[un];
        }

        const float s2l = p * sc2;
        corr = fmaf(s2l, 128.f, corr);
#pragma unroll
        for (int c = 0; c < 4; ++c)
#pragma unroll
            for (int k = 0; k < 4; ++k)
                acc[c][k] = fmaf(s2l, ub(d2[c], k), acc[c][k]);

        node = next;
        d1 = nd1; d2 = nd2; sc1 = ns1; sc2 = ns2;
    }

    f32x4* y4 = reinterpret_cast<f32x4*>(y + (size_t)row * FFF_NOUT);
#pragma unroll
    for (int c = 0; c < 4; ++c) {
        f32x4 o;
        o[0] = acc[c][0] - corr; o[1] = acc[c][1] - corr;
        o[2] = acc[c][2] - corr; o[3] = acc[c][3] - corr;
        __builtin_nontemporal_store(o, &y4[c * 64 + lane]);
    }
}

// ---- last-resort fp32 fallback ----
__global__ __launch_bounds__(256, 4) void fff_fused_f32(
    const float* __restrict__ x, const float* __restrict__ w1s,
    const float* __restrict__ w2s, float* __restrict__ y)
{
    const int row  = blockIdx.x * 4 + (threadIdx.x >> 6);
    const int lane = threadIdx.x & 63;
    const f32x4* x4 = reinterpret_cast<const f32x4*>(x + (size_t)row * FFF_NIN);
    f32x4 xv[4];
#pragma unroll
    for (int c = 0; c < 4; ++c) xv[c] = x4[c * 64 + lane];
    f32x4 acc[4];
#pragma unroll
    for (int c = 0; c < 4; ++c) acc[c] = (f32x4)(0.f);
    int node = 0;
#pragma unroll 1
    for (int l = 0; l < FFF_LEVELS; ++l) {
        const f32x4* w14 = reinterpret_cast<const f32x4*>(w1s + (size_t)node * FFF_NIN);
        const f32x4* w24 = reinterpret_cast<const f32x4*>(w2s + (size_t)node * FFF_NOUT);
        f32x4 wv[4], uv[4];
#pragma unroll
        for (int c = 0; c < 4; ++c) { wv[c] = w14[c * 64 + lane]; uv[c] = w24[c * 64 + lane]; }
        float p = 0.f;
#pragma unroll
        for (int c = 0; c < 4; ++c) {
            p = fmaf(xv[c][0], wv[c][0], p); p = fmaf(xv[c][1], wv[c][1], p);
            p = fmaf(xv[c][2], wv[c][2], p); p = fmaf(xv[c][3], wv[c][3], p);
        }
#pragma unroll
        for (int m = 1; m < 64; m <<= 1) p += __shfl_xor(p, m, 64);
#pragma unroll
        for (int c = 0; c < 4; ++c) {
            acc[c][0] = fmaf(p, uv[c][0], acc[c][0]); acc[c][1] = fmaf(p, uv[c][1], acc[c][1]);
            acc[c][2] = fmaf(p, uv[c][2], acc[c][2]); acc[c][3] = fmaf(p, uv[c][3], acc[c][3]);
        }
        node = node * 2 + 1 + ((p > 0.f) ? 1 : 0);
    }
    f32x4* y4 = reinterpret_cast<f32x4*>(y + (size_t)row * FFF_NOUT);
#pragma unroll
    for (int c = 0; c < 4; ++c) y4[c * 64 + lane] = acc[c];
}

extern "C" void kernel_launch(void* const* d_in, const int* in_sizes, int n_in,
                              void* d_out, int out_size, void* d_ws, size_t ws_size,
                              hipStream_t stream) {
    const float* x   = (const float*)d_in[0];
    const float* w1s = (const float*)d_in[1];
    const float* w2s = (const float*)d_in[2];
    float* y = (float*)d_out;

    // ws layout (all 16B multiples):
    const size_t off_s1     = 0;                 // 8192
    const size_t off_s2     = 8192;              // 8192
    const size_t off_q1     = 16384;             // 2,096,128
    const size_t off_q2     = off_q1 + 2096128;  // 2,096,128
    const size_t off_xqs    = off_q2 + 2096128;  // 33,554,432
    const size_t off_meta   = off_xqs + 33554432;// 1,048,576
    const size_t off_perm   = off_meta + 1048576;// 131,072
    const size_t off_hist   = off_perm + 131072; // 256
    const size_t off_start  = off_hist + 256;    // 256
    const size_t off_cursor = off_start + 256;   // 256
    const size_t need_full  = off_cursor + 256;  // ~38.9 MB
    const size_t need_small = off_xqs;           // ~4.2 MB (r16 path)

    char* w = (char*)d_ws;
    float* s1 = (float*)(w + off_s1);
    float* s2 = (float*)(w + off_s2);
    unsigned char* q1 = (unsigned char*)(w + off_q1);
    unsigned char* q2 = (unsigned char*)(w + off_q2);

    if (ws_size >= need_full) {
        u32x4* xqs4  = (u32x4*)(w + off_xqs);
        float* meta  = (float*)(w + off_meta);
        int*   perm  = (int*)(w + off_perm);
        int*   hist  = (int*)(w + off_hist);
        int*   start = (int*)(w + off_start);
        int*   curs  = (int*)(w + off_cursor);

        fff_quant_u8<<<FFF_NODES, 256, 0, stream>>>(w1s, w2s, q1, q2, s1, s2);
        fff_zero<<<1, 64, 0, stream>>>(hist);
        fff_phase1<<<512, 512, 0, stream>>>(x, q1, s1, w1s, xqs4, meta, hist);
        fff_scan<<<1, 64, 0, stream>>>(hist, start, curs);
        fff_scatter<<<FFF_BATCH / 256, 256, 0, stream>>>(meta, curs, perm);
        fff_phase2<<<512, 512, 0, stream>>>(x, w1s, q1, q2, s1, s2,
                                            xqs4, meta, perm, start, y);
    } else if (ws_size >= need_small) {
        fff_quant_u8<<<FFF_NODES, 256, 0, stream>>>(w1s, w2s, q1, q2, s1, s2);
        fff_main_u8<<<FFF_BATCH / 4, 256, 0, stream>>>(x, q1, s1, w1s, q2, s2, y);
    } else {
        fff_fused_f32<<<FFF_BATCH / 4, 256, 0, stream>>>(x, w1s, w2s, y);
    }
}

// Round 19
// 87.513 us; speedup vs baseline: 4.1389x; 4.1389x over previous
//
#include <hip/hip_runtime.h>

// FFF tree traversal, round 19: r16 structure (proven best, 75.4us main)
// with levels 0-3 (nodes 0..14, w1+w2 = 30KB) cached in LDS.
// Unlike r18 (65KB LDS -> 2 blocks/CU -> 32% occupancy -> disaster), 30KB
// preserves 5 blocks/CU = the residency r16 actually achieves -> occupancy
// neutral. Shallow gathers (36% of level-iters, max same-address contention)
// become ~120cy LDS reads instead of ~500cy L2/L3 gathers. Levels 4-10 are
// the r16 body verbatim (level-4 row prefetched inside the l=3 iteration).
// Bytes + arithmetic identical to r16 -> absmax 0.0234375 unchanged.
// Null result => wall is deep-gather-specific; next: persistent grid.

typedef float        f32x4 __attribute__((ext_vector_type(4)));
typedef unsigned int u32x4 __attribute__((ext_vector_type(4)));

#define FFF_BATCH  32768
#define FFF_NIN    1024
#define FFF_NOUT   1024
#define FFF_LEVELS 11
#define FFF_NODES  2047
#define FFF_EPS    0.035f

__device__ __forceinline__ f32x4 ld_nt4f(const f32x4* p) { return __builtin_nontemporal_load(p); }
__device__ __forceinline__ float ub(unsigned d, int k) {
    return (float)((d >> (8 * k)) & 0xffu);   // -> v_cvt_f32_ubyte[k]
}

__device__ __forceinline__ int sdot4(unsigned a, unsigned b, int c) {
#if __has_builtin(__builtin_amdgcn_sdot4)
    return __builtin_amdgcn_sdot4((int)a, (int)b, c, false);
#else
#pragma unroll
    for (int k = 0; k < 4; ++k) {
        const int ai = (int)(a << (24 - 8 * k)) >> 24;
        const int bi = (int)(b << (24 - 8 * k)) >> 24;
        c += ai * bi;
    }
    return c;
#endif
}

template<int CTRL>
__device__ __forceinline__ float dpp_add(float v) {
    const int t = __builtin_amdgcn_update_dpp(0, __float_as_int(v), CTRL, 0xF, 0xF, true);
    return v + __int_as_float(t);
}
__device__ __forceinline__ float wave_sum(float v) {
    v = dpp_add<0x111>(v); v = dpp_add<0x112>(v);
    v = dpp_add<0x114>(v); v = dpp_add<0x118>(v);
    v = dpp_add<0x142>(v); v = dpp_add<0x143>(v);
    return __int_as_float(__builtin_amdgcn_readlane(__float_as_int(v), 63));
}
template<int CTRL>
__device__ __forceinline__ int dpp_addi(int v) {
    return v + __builtin_amdgcn_update_dpp(0, v, CTRL, 0xF, 0xF, true);
}
__device__ __forceinline__ int wave_sum_i(int v) {
    v = dpp_addi<0x111>(v); v = dpp_addi<0x112>(v);
    v = dpp_addi<0x114>(v); v = dpp_addi<0x118>(v);
    v = dpp_addi<0x142>(v); v = dpp_addi<0x143>(v);
    return __builtin_amdgcn_readlane(v, 63);
}
template<int CTRL>
__device__ __forceinline__ float dpp_max(float v) {
    const int t = __builtin_amdgcn_update_dpp(0, __float_as_int(v), CTRL, 0xF, 0xF, true);
    return fmaxf(v, __int_as_float(t));
}
__device__ __forceinline__ float wave_max(float v) {   // v >= 0
    v = dpp_max<0x111>(v); v = dpp_max<0x112>(v);
    v = dpp_max<0x114>(v); v = dpp_max<0x118>(v);
    v = dpp_max<0x142>(v); v = dpp_max<0x143>(v);
    return __int_as_float(__builtin_amdgcn_readlane(__float_as_int(v), 63));
}

// ---- prep: w1 -> signed i8, w2 -> biased u8 (r16 verbatim) ----
__global__ void fff_quant_u8(const float* __restrict__ w1, const float* __restrict__ w2,
                             unsigned char* __restrict__ q1, unsigned char* __restrict__ q2,
                             float* __restrict__ s1, float* __restrict__ s2)
{
    const int node = blockIdx.x;
    const int t    = threadIdx.x;          // 256
    const int wave = t >> 6;
    const int lane = t & 63;

    const f32x4* r1 = reinterpret_cast<const f32x4*>(w1 + (size_t)node * FFF_NIN);
    const f32x4* r2 = reinterpret_cast<const f32x4*>(w2 + (size_t)node * FFF_NOUT);
    const int si = 64 * (t & 3) + (t >> 2);
    const f32x4 v1 = r1[si];
    const f32x4 v2 = r2[si];

    float m1 = 0.f, m2 = 0.f;
#pragma unroll
    for (int k = 0; k < 4; ++k) {
        m1 = fmaxf(m1, fabsf(v1[k]));
        m2 = fmaxf(m2, fabsf(v2[k]));
    }
#pragma unroll
    for (int m = 1; m < 64; m <<= 1) {
        m1 = fmaxf(m1, __shfl_xor(m1, m, 64));
        m2 = fmaxf(m2, __shfl_xor(m2, m, 64));
    }
    __shared__ float sm1[4], sm2[4];
    if (lane == 0) { sm1[wave] = m1; sm2[wave] = m2; }
    __syncthreads();
    m1 = fmaxf(fmaxf(sm1[0], sm1[1]), fmaxf(sm1[2], sm1[3]));
    m2 = fmaxf(fmaxf(sm2[0], sm2[1]), fmaxf(sm2[2], sm2[3]));

    const float st1 = (m1 > 0.f) ? m1 / 127.f : 1.f;
    const float st2 = (m2 > 0.f) ? m2 / 127.f : 1.f;
    if (t == 0) { s1[node] = st1; s2[node] = st2; }

    unsigned d1 = 0, d2 = 0;
#pragma unroll
    for (int k = 0; k < 4; ++k) {
        const int i1 = (int)rintf(v1[k] / st1);
        const int u2 = (int)rintf(v2[k] / st2) + 128;
        d1 |= ((unsigned)i1 & 0xffu) << (8 * k);
        d2 |= ((unsigned)u2 & 0xffu) << (8 * k);
    }
    reinterpret_cast<unsigned*>(q1)[(size_t)node * 256 + t] = d1;
    reinterpret_cast<unsigned*>(q2)[(size_t)node * 256 + t] = d2;
}

// ---- main fused kernel: r16 + LDS cache for nodes 0..14 (levels 0-3) ----
__global__ __launch_bounds__(256, 8) void fff_main_u8(
    const float*         __restrict__ x,
    const unsigned char* __restrict__ q1,
    const float*         __restrict__ s1,
    const float*         __restrict__ w1f,   // fp32 w1 for the EPS fallback
    const unsigned char* __restrict__ q2,
    const float*         __restrict__ s2,
    float*               __restrict__ y)
{
    __shared__ unsigned char lw1[15 * 1024];
    __shared__ unsigned char lw2[15 * 1024];
    __shared__ float ls1[16], ls2[16];

    const int tid  = threadIdx.x;
    const int row  = blockIdx.x * 4 + (tid >> 6);
    const int lane = tid & 63;

    // stage nodes 0..14 (contiguous 15KB in each of q1,q2) into LDS
    for (int i = tid; i < 15 * 64; i += 256) {
        reinterpret_cast<u32x4*>(lw1)[i] = reinterpret_cast<const u32x4*>(q1)[i];
        reinterpret_cast<u32x4*>(lw2)[i] = reinterpret_cast<const u32x4*>(q2)[i];
    }
    if (tid < 15) { ls1[tid] = s1[tid]; ls2[tid] = s2[tid]; }

    // coalesced x: xv[c] = elements 256c + 4*lane ..+3 (overlaps staging)
    const f32x4* x4 = reinterpret_cast<const f32x4*>(x + (size_t)row * FFF_NIN);
    f32x4 xv[4];
#pragma unroll
    for (int c = 0; c < 4; ++c) xv[c] = ld_nt4f(&x4[c * 64 + lane]);

    // per-row i8 quantization of x (uniform scale via DPP max-reduce)
    float mx = 0.f;
#pragma unroll
    for (int c = 0; c < 4; ++c)
#pragma unroll
        for (int k = 0; k < 4; ++k) mx = fmaxf(mx, fabsf(xv[c][k]));
    mx = wave_max(mx);
    const float stx = (mx > 0.f) ? mx / 127.f : 1.f;
    const float inv = (mx > 0.f) ? 127.f / mx : 0.f;

    unsigned xq[4];
#pragma unroll
    for (int c = 0; c < 4; ++c) {
        const int a0 = (int)rintf(xv[c][0] * inv);
        const int a1 = (int)rintf(xv[c][1] * inv);
        const int a2 = (int)rintf(xv[c][2] * inv);
        const int a3 = (int)rintf(xv[c][3] * inv);
        xq[c] = ((unsigned)a0 & 0xffu) | (((unsigned)a1 & 0xffu) << 8) |
                (((unsigned)a2 & 0xffu) << 16) | (((unsigned)a3 & 0xffu) << 24);
    }

    f32x4 acc[4];
#pragma unroll
    for (int c = 0; c < 4; ++c) acc[c] = (f32x4)(0.f);
    float corr = 0.f;

    const u32x4* q1v = reinterpret_cast<const u32x4*>(q1);  // node*64 + lane
    const u32x4* q2v = reinterpret_cast<const u32x4*>(q2);

    __syncthreads();   // staging complete

    int node = 0;
    u32x4 d1g, d2g;                  // prefetch regs for level 4
    float ns1 = 0.f, ns2 = 0.f;

    // ---- levels 0..3 from LDS ----
#pragma unroll 1
    for (int l = 0; l < 4; ++l) {
        const u32x4 d1 = *reinterpret_cast<const u32x4*>(lw1 + (size_t)node * 1024 + lane * 16);
        const u32x4 d2 = *reinterpret_cast<const u32x4*>(lw2 + (size_t)node * 1024 + lane * 16);
        const float sc1 = ls1[node];
        const float sc2 = ls2[node];

        int idot = 0;
#pragma unroll
        for (int c = 0; c < 4; ++c) idot = sdot4(xq[c], d1[c], idot);
        float p = (float)wave_sum_i(idot) * (stx * sc1);

        if (__builtin_expect(fabsf(p) < FFF_EPS, 0)) {
            const f32x4* w14 = reinterpret_cast<const f32x4*>(w1f + (size_t)node * FFF_NIN);
            float s = 0.f;
#pragma unroll
            for (int c = 0; c < 4; ++c) {
                const f32x4 w = w14[c * 64 + lane];
                s = fmaf(xv[c][0], w[0], s); s = fmaf(xv[c][1], w[1], s);
                s = fmaf(xv[c][2], w[2], s); s = fmaf(xv[c][3], w[3], s);
            }
            p = wave_sum(s);
        }

        const int next = 2 * node + 1 + ((p > 0.f) ? 1 : 0);
        if (l == 3) {   // prefetch level-4 row from global before the accum
            const int un = __builtin_amdgcn_readfirstlane(next);
            d1g = q1v[(size_t)un * 64 + lane];
            d2g = q2v[(size_t)un * 64 + lane];
            ns1 = s1[un];
            ns2 = s2[un];
        }

        const float s2l = p * sc2;
        corr = fmaf(s2l, 128.f, corr);
#pragma unroll
        for (int c = 0; c < 4; ++c)
#pragma unroll
            for (int k = 0; k < 4; ++k)
                acc[c][k] = fmaf(s2l, ub(d2[c], k), acc[c][k]);

        node = next;
    }

    // ---- levels 4..10 from global (r16 body verbatim) ----
    u32x4 d1 = d1g, d2 = d2g;
    float sc1 = ns1, sc2 = ns2;

#pragma unroll 1
    for (int l = 4; l < FFF_LEVELS; ++l) {
        int idot = 0;
#pragma unroll
        for (int c = 0; c < 4; ++c) idot = sdot4(xq[c], d1[c], idot);
        float p = (float)wave_sum_i(idot) * (stx * sc1);

        if (__builtin_expect(fabsf(p) < FFF_EPS, 0)) {
            const f32x4* w14 = reinterpret_cast<const f32x4*>(w1f + (size_t)node * FFF_NIN);
            float s = 0.f;
#pragma unroll
            for (int c = 0; c < 4; ++c) {
                const f32x4 w = w14[c * 64 + lane];
                s = fmaf(xv[c][0], w[0], s); s = fmaf(xv[c][1], w[1], s);
                s = fmaf(xv[c][2], w[2], s); s = fmaf(xv[c][3], w[3], s);
            }
            p = wave_sum(s);
        }

        const int next = 2 * node + 1 + ((p > 0.f) ? 1 : 0);
        u32x4 nd1 = d1, nd2 = d2;
        float nns1 = sc1, nns2 = sc2;
        if (l < FFF_LEVELS - 1) {
            const int un = __builtin_amdgcn_readfirstlane(next);
            nd1 = q1v[(size_t)un * 64 + lane];
            nd2 = q2v[(size_t)un * 64 + lane];
            nns1 = s1[un];
            nns2 = s2[un];
        }

        const float s2l = p * sc2;
        corr = fmaf(s2l, 128.f, corr);
#pragma unroll
        for (int c = 0; c < 4; ++c)
#pragma unroll
            for (int k = 0; k < 4; ++k)
                acc[c][k] = fmaf(s2l, ub(d2[c], k), acc[c][k]);

        node = next;
        d1 = nd1; d2 = nd2; sc1 = nns1; sc2 = nns2;
    }

    // coalesced nontemporal y stores (full 128B lines; keep L2 for weights)
    f32x4* y4 = reinterpret_cast<f32x4*>(y + (size_t)row * FFF_NOUT);
#pragma unroll
    for (int c = 0; c < 4; ++c) {
        f32x4 o;
        o[0] = acc[c][0] - corr; o[1] = acc[c][1] - corr;
        o[2] = acc[c][2] - corr; o[3] = acc[c][3] - corr;
        __builtin_nontemporal_store(o, &y4[c * 64 + lane]);
    }
}

// ---- last-resort fp32 fallback ----
__global__ __launch_bounds__(256, 4) void fff_fused_f32(
    const float* __restrict__ x, const float* __restrict__ w1s,
    const float* __restrict__ w2s, float* __restrict__ y)
{
    const int row  = blockIdx.x * 4 + (threadIdx.x >> 6);
    const int lane = threadIdx.x & 63;
    const f32x4* x4 = reinterpret_cast<const f32x4*>(x + (size_t)row * FFF_NIN);
    f32x4 xv[4];
#pragma unroll
    for (int c = 0; c < 4; ++c) xv[c] = x4[c * 64 + lane];
    f32x4 acc[4];
#pragma unroll
    for (int c = 0; c < 4; ++c) acc[c] = (f32x4)(0.f);
    int node = 0;
#pragma unroll 1
    for (int l = 0; l < FFF_LEVELS; ++l) {
        const f32x4* w14 = reinterpret_cast<const f32x4*>(w1s + (size_t)node * FFF_NIN);
        const f32x4* w24 = reinterpret_cast<const f32x4*>(w2s + (size_t)node * FFF_NOUT);
        f32x4 wv[4], uv[4];
#pragma unroll
        for (int c = 0; c < 4; ++c) { wv[c] = w14[c * 64 + lane]; uv[c] = w24[c * 64 + lane]; }
        float p = 0.f;
#pragma unroll
        for (int c = 0; c < 4; ++c) {
            p = fmaf(xv[c][0], wv[c][0], p); p = fmaf(xv[c][1], wv[c][1], p);
            p = fmaf(xv[c][2], wv[c][2], p); p = fmaf(xv[c][3], wv[c][3], p);
        }
#pragma unroll
        for (int m = 1; m < 64; m <<= 1) p += __shfl_xor(p, m, 64);
#pragma unroll
        for (int c = 0; c < 4; ++c) {
            acc[c][0] = fmaf(p, uv[c][0], acc[c][0]); acc[c][1] = fmaf(p, uv[c][1], acc[c][1]);
            acc[c][2] = fmaf(p, uv[c][2], acc[c][2]); acc[c][3] = fmaf(p, uv[c][3], acc[c][3]);
        }
        node = node * 2 + 1 + ((p > 0.f) ? 1 : 0);
    }
    f32x4* y4 = reinterpret_cast<f32x4*>(y + (size_t)row * FFF_NOUT);
#pragma unroll
    for (int c = 0; c < 4; ++c) y4[c * 64 + lane] = acc[c];
}

extern "C" void kernel_launch(void* const* d_in, const int* in_sizes, int n_in,
                              void* d_out, int out_size, void* d_ws, size_t ws_size,
                              hipStream_t stream) {
    const float* x   = (const float*)d_in[0];
    const float* w1s = (const float*)d_in[1];
    const float* w2s = (const float*)d_in[2];
    float* y = (float*)d_out;

    // ws layout (16B-aligned blocks): s1 | s2 | q1 | q2
    const size_t sc_bytes = 8192;                              // 2047 floats, padded
    const size_t q_bytes  = (size_t)FFF_NODES * 1024;          // 2,096,128
    const size_t need = 2 * sc_bytes + 2 * q_bytes;            // ~4.21 MB

    if (ws_size >= need) {
        float* s1 = (float*)d_ws;
        float* s2 = (float*)((char*)d_ws + sc_bytes);
        unsigned char* q1 = (unsigned char*)d_ws + 2 * sc_bytes;
        unsigned char* q2 = q1 + q_bytes;
        fff_quant_u8<<<FFF_NODES, 256, 0, stream>>>(w1s, w2s, q1, q2, s1, s2);
        fff_main_u8<<<FFF_BATCH / 4, 256, 0, stream>>>(x, q1, s1, w1s, q2, s2, y);
    } else {
        fff_fused_f32<<<FFF_BATCH / 4, 256, 0, stream>>>(x, w1s, w2s, y);
    }
}

// Round 20
// 82.542 us; speedup vs baseline: 4.3881x; 1.0602x over previous
//
#include <hip/hip_runtime.h>

// FFF tree traversal, FINAL (= round-16 kernel, proven best: 82.7us total,
// 75.4us main). Search summary across 19 rounds:
//   WINS: per-node u8 weight quantization (i8 w1 + sdot4 dot; biased-u8 w2
//         with scalar bias correction) — 2x, the single biggest lever;
//         DPP wave reduce (VALU pipe, ~50cy vs ~240cy ds_swizzle chain);
//         next-level load issued before y-accum (hides gather latency);
//         rolled level loop (full unroll -> 64B/thread scratch spill);
//         nt x loads + nt y stores (keep L2 for weights; FETCH -20%).
//   REFUTED: in-wave ILP2 (r2/r5/r6 spill, r14 occupancy/serialization);
//         both-children prefetch (r11/r15: extra gather traffic loses);
//         LDS weight residency (r18/r19: occupancy cost > latency saved);
//         finer blocks / interleaved layout (r17).
//   Residual: main pinned ~75us by the 11-level serially-dependent gather
//         chain (nothing saturated: VALU 50%, HBM 42%, occ 63%) — a
//         latency wall of the algorithm's sequential structure, ~1.8x the
//         268MB compulsory-HBM floor (42us).
// Numerics: absmax 0.0234 vs threshold 0.0438 (EPS=0.035 fp32 sign
// fallback; x-quant sigma 7x below the decision margin).

typedef float        f32x4 __attribute__((ext_vector_type(4)));
typedef unsigned int u32x4 __attribute__((ext_vector_type(4)));

#define FFF_BATCH  32768
#define FFF_NIN    1024
#define FFF_NOUT   1024
#define FFF_LEVELS 11
#define FFF_NODES  2047
#define FFF_EPS    0.035f

__device__ __forceinline__ f32x4 ld_nt4f(const f32x4* p) { return __builtin_nontemporal_load(p); }
__device__ __forceinline__ float ub(unsigned d, int k) {
    return (float)((d >> (8 * k)) & 0xffu);   // -> v_cvt_f32_ubyte[k]
}

__device__ __forceinline__ int sdot4(unsigned a, unsigned b, int c) {
#if __has_builtin(__builtin_amdgcn_sdot4)
    return __builtin_amdgcn_sdot4((int)a, (int)b, c, false);
#else
#pragma unroll
    for (int k = 0; k < 4; ++k) {
        const int ai = (int)(a << (24 - 8 * k)) >> 24;
        const int bi = (int)(b << (24 - 8 * k)) >> 24;
        c += ai * bi;
    }
    return c;
#endif
}

template<int CTRL>
__device__ __forceinline__ float dpp_add(float v) {
    const int t = __builtin_amdgcn_update_dpp(0, __float_as_int(v), CTRL, 0xF, 0xF, true);
    return v + __int_as_float(t);
}
__device__ __forceinline__ float wave_sum(float v) {
    v = dpp_add<0x111>(v); v = dpp_add<0x112>(v);
    v = dpp_add<0x114>(v); v = dpp_add<0x118>(v);
    v = dpp_add<0x142>(v); v = dpp_add<0x143>(v);
    return __int_as_float(__builtin_amdgcn_readlane(__float_as_int(v), 63));
}
template<int CTRL>
__device__ __forceinline__ int dpp_addi(int v) {
    return v + __builtin_amdgcn_update_dpp(0, v, CTRL, 0xF, 0xF, true);
}
__device__ __forceinline__ int wave_sum_i(int v) {
    v = dpp_addi<0x111>(v); v = dpp_addi<0x112>(v);
    v = dpp_addi<0x114>(v); v = dpp_addi<0x118>(v);
    v = dpp_addi<0x142>(v); v = dpp_addi<0x143>(v);
    return __builtin_amdgcn_readlane(v, 63);
}
template<int CTRL>
__device__ __forceinline__ float dpp_max(float v) {
    const int t = __builtin_amdgcn_update_dpp(0, __float_as_int(v), CTRL, 0xF, 0xF, true);
    return fmaxf(v, __int_as_float(t));
}
__device__ __forceinline__ float wave_max(float v) {   // v >= 0
    v = dpp_max<0x111>(v); v = dpp_max<0x112>(v);
    v = dpp_max<0x114>(v); v = dpp_max<0x118>(v);
    v = dpp_max<0x142>(v); v = dpp_max<0x143>(v);
    return __int_as_float(__builtin_amdgcn_readlane(__float_as_int(v), 63));
}

// ---- prep: w1 -> signed i8, w2 -> biased u8 (one block per node) ----
// byte b = 4*t + k of node's 1024B row <- src elem 256*(t&3) + 4*(t>>2) + k,
// so in main, lane's dwords 4*lane..+3 pair with xq[c][k] <- x[256c+4*lane+k].
__global__ void fff_quant_u8(const float* __restrict__ w1, const float* __restrict__ w2,
                             unsigned char* __restrict__ q1, unsigned char* __restrict__ q2,
                             float* __restrict__ s1, float* __restrict__ s2)
{
    const int node = blockIdx.x;
    const int t    = threadIdx.x;          // 256
    const int wave = t >> 6;
    const int lane = t & 63;

    const f32x4* r1 = reinterpret_cast<const f32x4*>(w1 + (size_t)node * FFF_NIN);
    const f32x4* r2 = reinterpret_cast<const f32x4*>(w2 + (size_t)node * FFF_NOUT);
    const int si = 64 * (t & 3) + (t >> 2);
    const f32x4 v1 = r1[si];
    const f32x4 v2 = r2[si];

    float m1 = 0.f, m2 = 0.f;
#pragma unroll
    for (int k = 0; k < 4; ++k) {
        m1 = fmaxf(m1, fabsf(v1[k]));
        m2 = fmaxf(m2, fabsf(v2[k]));
    }
#pragma unroll
    for (int m = 1; m < 64; m <<= 1) {
        m1 = fmaxf(m1, __shfl_xor(m1, m, 64));
        m2 = fmaxf(m2, __shfl_xor(m2, m, 64));
    }
    __shared__ float sm1[4], sm2[4];
    if (lane == 0) { sm1[wave] = m1; sm2[wave] = m2; }
    __syncthreads();
    m1 = fmaxf(fmaxf(sm1[0], sm1[1]), fmaxf(sm1[2], sm1[3]));
    m2 = fmaxf(fmaxf(sm2[0], sm2[1]), fmaxf(sm2[2], sm2[3]));

    const float st1 = (m1 > 0.f) ? m1 / 127.f : 1.f;
    const float st2 = (m2 > 0.f) ? m2 / 127.f : 1.f;
    if (t == 0) { s1[node] = st1; s2[node] = st2; }

    unsigned d1 = 0, d2 = 0;
#pragma unroll
    for (int k = 0; k < 4; ++k) {
        const int i1 = (int)rintf(v1[k] / st1);         // signed, [-127,127]
        const int u2 = (int)rintf(v2[k] / st2) + 128;   // biased, [1,255]
        d1 |= ((unsigned)i1 & 0xffu) << (8 * k);
        d2 |= ((unsigned)u2 & 0xffu) << (8 * k);
    }
    reinterpret_cast<unsigned*>(q1)[(size_t)node * 256 + t] = d1;
    reinterpret_cast<unsigned*>(q2)[(size_t)node * 256 + t] = d2;
}

// ---- main fused kernel: 1 row/wave, rolled level loop, 8 waves/EU ----
__global__ __launch_bounds__(256, 8) void fff_main_u8(
    const float*         __restrict__ x,
    const unsigned char* __restrict__ q1,
    const float*         __restrict__ s1,
    const float*         __restrict__ w1f,   // fp32 w1 for the EPS fallback
    const unsigned char* __restrict__ q2,
    const float*         __restrict__ s2,
    float*               __restrict__ y)
{
    const int row  = blockIdx.x * 4 + (threadIdx.x >> 6);
    const int lane = threadIdx.x & 63;

    // coalesced x: xv[c] = elements 256c + 4*lane ..+3
    const f32x4* x4 = reinterpret_cast<const f32x4*>(x + (size_t)row * FFF_NIN);
    f32x4 xv[4];
#pragma unroll
    for (int c = 0; c < 4; ++c) xv[c] = ld_nt4f(&x4[c * 64 + lane]);

    // per-row i8 quantization of x (uniform scale via DPP max-reduce)
    float mx = 0.f;
#pragma unroll
    for (int c = 0; c < 4; ++c)
#pragma unroll
        for (int k = 0; k < 4; ++k) mx = fmaxf(mx, fabsf(xv[c][k]));
    mx = wave_max(mx);
    const float stx = (mx > 0.f) ? mx / 127.f : 1.f;
    const float inv = (mx > 0.f) ? 127.f / mx : 0.f;

    unsigned xq[4];
#pragma unroll
    for (int c = 0; c < 4; ++c) {
        const int a0 = (int)rintf(xv[c][0] * inv);
        const int a1 = (int)rintf(xv[c][1] * inv);
        const int a2 = (int)rintf(xv[c][2] * inv);
        const int a3 = (int)rintf(xv[c][3] * inv);
        xq[c] = ((unsigned)a0 & 0xffu) | (((unsigned)a1 & 0xffu) << 8) |
                (((unsigned)a2 & 0xffu) << 16) | (((unsigned)a3 & 0xffu) << 24);
    }

    f32x4 acc[4];
#pragma unroll
    for (int c = 0; c < 4; ++c) acc[c] = (f32x4)(0.f);
    float corr = 0.f;

    const u32x4* q1v = reinterpret_cast<const u32x4*>(q1);  // node*64 + lane
    const u32x4* q2v = reinterpret_cast<const u32x4*>(q2);

    int node = 0;
    u32x4 d1 = q1v[lane];
    u32x4 d2 = q2v[lane];
    float sc1 = s1[0];
    float sc2 = s2[0];

#pragma unroll 1
    for (int l = 0; l < FFF_LEVELS; ++l) {
        // ---- i8 dot: 4 sdot4 per lane, exact i32 ----
        int idot = 0;
#pragma unroll
        for (int c = 0; c < 4; ++c) idot = sdot4(xq[c], d1[c], idot);

        // ---- DPP integer reduce; score uniform ----
        float p = (float)wave_sum_i(idot) * (stx * sc1);

        // ---- rare wave-uniform fp32 recompute for near-zero scores ----
        if (__builtin_expect(fabsf(p) < FFF_EPS, 0)) {
            const f32x4* w14 = reinterpret_cast<const f32x4*>(w1f + (size_t)node * FFF_NIN);
            float s = 0.f;
#pragma unroll
            for (int c = 0; c < 4; ++c) {
                const f32x4 w = w14[c * 64 + lane];
                s = fmaf(xv[c][0], w[0], s);
                s = fmaf(xv[c][1], w[1], s);
                s = fmaf(xv[c][2], w[2], s);
                s = fmaf(xv[c][3], w[3], s);
            }
            p = wave_sum(s);
        }

        // ---- advance + issue next level's loads before the y-accum ----
        const int next = 2 * node + 1 + ((p > 0.f) ? 1 : 0);
        u32x4 nd1 = d1, nd2 = d2;
        float ns1 = sc1, ns2 = sc2;
        if (l < FFF_LEVELS - 1) {
            const int un = __builtin_amdgcn_readfirstlane(next);
            nd1 = q1v[(size_t)un * 64 + lane];
            nd2 = q2v[(size_t)un * 64 + lane];
            ns1 = s1[un];
            ns2 = s2[un];
        }

        // ---- y accumulate (hides the child-load latency) ----
        const float s2l = p * sc2;
        corr = fmaf(s2l, 128.f, corr);
#pragma unroll
        for (int c = 0; c < 4; ++c) {
#pragma unroll
            for (int k = 0; k < 4; ++k)
                acc[c][k] = fmaf(s2l, ub(d2[c], k), acc[c][k]);
        }

        node = next;
        d1 = nd1; d2 = nd2; sc1 = ns1; sc2 = ns2;
    }

    // coalesced nontemporal y stores (full 128B lines; keep L2 for weights)
    f32x4* y4 = reinterpret_cast<f32x4*>(y + (size_t)row * FFF_NOUT);
#pragma unroll
    for (int c = 0; c < 4; ++c) {
        f32x4 o;
        o[0] = acc[c][0] - corr; o[1] = acc[c][1] - corr;
        o[2] = acc[c][2] - corr; o[3] = acc[c][3] - corr;
        __builtin_nontemporal_store(o, &y4[c * 64 + lane]);
    }
}

// ---- safety fallback: proven round-1 fp32 fused kernel ----
__global__ __launch_bounds__(256, 4) void fff_fused_f32(
    const float* __restrict__ x, const float* __restrict__ w1s,
    const float* __restrict__ w2s, float* __restrict__ y)
{
    const int row  = blockIdx.x * 4 + (threadIdx.x >> 6);
    const int lane = threadIdx.x & 63;
    const f32x4* x4 = reinterpret_cast<const f32x4*>(x + (size_t)row * FFF_NIN);
    f32x4 xv[4];
#pragma unroll
    for (int c = 0; c < 4; ++c) xv[c] = x4[c * 64 + lane];
    f32x4 acc[4];
#pragma unroll
    for (int c = 0; c < 4; ++c) acc[c] = (f32x4)(0.f);
    int node = 0;
#pragma unroll 1
    for (int l = 0; l < FFF_LEVELS; ++l) {
        const f32x4* w14 = reinterpret_cast<const f32x4*>(w1s + (size_t)node * FFF_NIN);
        const f32x4* w24 = reinterpret_cast<const f32x4*>(w2s + (size_t)node * FFF_NOUT);
        f32x4 wv[4], uv[4];
#pragma unroll
        for (int c = 0; c < 4; ++c) { wv[c] = w14[c * 64 + lane]; uv[c] = w24[c * 64 + lane]; }
        float p = 0.f;
#pragma unroll
        for (int c = 0; c < 4; ++c) {
            p = fmaf(xv[c][0], wv[c][0], p); p = fmaf(xv[c][1], wv[c][1], p);
            p = fmaf(xv[c][2], wv[c][2], p); p = fmaf(xv[c][3], wv[c][3], p);
        }
#pragma unroll
        for (int m = 1; m < 64; m <<= 1) p += __shfl_xor(p, m, 64);
#pragma unroll
        for (int c = 0; c < 4; ++c) {
            acc[c][0] = fmaf(p, uv[c][0], acc[c][0]); acc[c][1] = fmaf(p, uv[c][1], acc[c][1]);
            acc[c][2] = fmaf(p, uv[c][2], acc[c][2]); acc[c][3] = fmaf(p, uv[c][3], acc[c][3]);
        }
        node = node * 2 + 1 + ((p > 0.f) ? 1 : 0);
    }
    f32x4* y4 = reinterpret_cast<f32x4*>(y + (size_t)row * FFF_NOUT);
#pragma unroll
    for (int c = 0; c < 4; ++c) y4[c * 64 + lane] = acc[c];
}

extern "C" void kernel_launch(void* const* d_in, const int* in_sizes, int n_in,
                              void* d_out, int out_size, void* d_ws, size_t ws_size,
                              hipStream_t stream) {
    const float* x   = (const float*)d_in[0];
    const float* w1s = (const float*)d_in[1];
    const float* w2s = (const float*)d_in[2];
    float* y = (float*)d_out;

    // ws layout (16B-aligned blocks): s1 | s2 | q1 | q2
    const size_t sc_bytes = 8192;                              // 2047 floats, padded
    const size_t q_bytes  = (size_t)FFF_NODES * 1024;          // 2,096,128
    const size_t need = 2 * sc_bytes + 2 * q_bytes;            // ~4.21 MB

    if (ws_size >= need) {
        float* s1 = (float*)d_ws;
        float* s2 = (float*)((char*)d_ws + sc_bytes);
        unsigned char* q1 = (unsigned char*)d_ws + 2 * sc_bytes;
        unsigned char* q2 = q1 + q_bytes;
        fff_quant_u8<<<FFF_NODES, 256, 0, stream>>>(w1s, w2s, q1, q2, s1, s2);
        fff_main_u8<<<FFF_BATCH / 4, 256, 0, stream>>>(x, q1, s1, w1s, q2, s2, y);
    } else {
        fff_fused_f32<<<FFF_BATCH / 4, 256, 0, stream>>>(x, w1s, w2s, y);
    }
}